// Round 1
// baseline (1625.100 us; speedup 1.0000x reference)
//
#include <hip/hip_runtime.h>

#define N_NODES 100000
#define E_EDGES 3200000
#define IN_F 128
#define ATT 128
#define HEADS 8
#define DK 16
#define SLOPE 0.2f

// ---------------------------------------------------------------------------
// K1: wx = x @ W   (100000x128 @ 128x128, fp32 vector FMA)
//     + fused epilogue: s_src[n][h] = sum_k wx[n][h*16+k]*a1[k], s_dst with a2
// Tile: 128 rows x 128 cols per block (256 threads), 8x8 per thread.
// ---------------------------------------------------------------------------
__global__ __launch_bounds__(256) void gemm_s_kernel(
    const float* __restrict__ x, const float* __restrict__ W,
    const float* __restrict__ a, float* __restrict__ wx,
    float* __restrict__ s_src, float* __restrict__ s_dst)
{
    __shared__ float xs[8][128];   // [k][row] transposed x tile
    __shared__ float Ws[8][128];   // [k][col]

    const int tid = threadIdx.x;
    const int ty  = tid >> 4;      // 0..15  -> row group (8 rows)
    const int tx  = tid & 15;      // 0..15  -> col group (8 cols)
    const int row0 = blockIdx.x * 128;

    float acc[8][8];
#pragma unroll
    for (int i = 0; i < 8; i++)
#pragma unroll
        for (int j = 0; j < 8; j++) acc[i][j] = 0.f;

    const int lrow  = tid >> 1;        // 0..127 row for x staging
    const int khalf = (tid & 1) * 4;   // 0 or 4
    const int wkk   = tid >> 5;        // 0..7 k-row for W staging
    const int wc    = (tid & 31) * 4;  // col*4

    for (int k0 = 0; k0 < IN_F; k0 += 8) {
        float4 xv = make_float4(0.f, 0.f, 0.f, 0.f);
        const int grow = row0 + lrow;
        if (grow < N_NODES)
            xv = *(const float4*)(x + (size_t)grow * IN_F + k0 + khalf);
        const float4 wv = *(const float4*)(W + (size_t)(k0 + wkk) * ATT + wc);

        __syncthreads();   // previous iter's reads done
        xs[khalf + 0][lrow] = xv.x;
        xs[khalf + 1][lrow] = xv.y;
        xs[khalf + 2][lrow] = xv.z;
        xs[khalf + 3][lrow] = xv.w;
        *(float4*)(&Ws[wkk][wc]) = wv;
        __syncthreads();

#pragma unroll
        for (int kk = 0; kk < 8; kk++) {
            float av[8], bv[8];
            *(float4*)(av)     = *(const float4*)(&xs[kk][ty * 8]);
            *(float4*)(av + 4) = *(const float4*)(&xs[kk][ty * 8 + 4]);
            *(float4*)(bv)     = *(const float4*)(&Ws[kk][tx * 8]);
            *(float4*)(bv + 4) = *(const float4*)(&Ws[kk][tx * 8 + 4]);
#pragma unroll
            for (int r = 0; r < 8; r++)
#pragma unroll
                for (int c = 0; c < 8; c++)
                    acc[r][c] = fmaf(av[r], bv[c], acc[r][c]);
        }
    }

    // Epilogue: store wx + fused s_src/s_dst.
    // Thread's 8 cols = [tx*8, tx*8+8) -> head = tx/2, k-offset = (tx&1)*8.
    const int koff = (tx & 1) * 8;
    const int head = tx >> 1;
    float a1[8], a2[8];
#pragma unroll
    for (int c = 0; c < 8; c++) {
        a1[c] = a[koff + c];
        a2[c] = a[DK + koff + c];
    }

#pragma unroll
    for (int r = 0; r < 8; r++) {
        const int grow = row0 + ty * 8 + r;
        const bool ok = (grow < N_NODES);
        if (ok) {
            *(float4*)(wx + (size_t)grow * ATT + tx * 8) =
                make_float4(acc[r][0], acc[r][1], acc[r][2], acc[r][3]);
            *(float4*)(wx + (size_t)grow * ATT + tx * 8 + 4) =
                make_float4(acc[r][4], acc[r][5], acc[r][6], acc[r][7]);
        }
        float p1 = 0.f, p2 = 0.f;
#pragma unroll
        for (int c = 0; c < 8; c++) {
            p1 = fmaf(acc[r][c], a1[c], p1);
            p2 = fmaf(acc[r][c], a2[c], p2);
        }
        p1 += __shfl_xor(p1, 1);
        p2 += __shfl_xor(p2, 1);
        if (((tx & 1) == 0) && ok) {
            s_src[(size_t)grow * HEADS + head] = p1;
            s_dst[(size_t)grow * HEADS + head] = p2;
        }
    }
}

// ---------------------------------------------------------------------------
// K2: per-edge exp(leakyrelu(score)) accumulated into denom[src][h]
// ---------------------------------------------------------------------------
__global__ __launch_bounds__(256) void denom_kernel(
    const int* __restrict__ src, const int* __restrict__ dst,
    const float* __restrict__ s_src, const float* __restrict__ s_dst,
    float* __restrict__ denom)
{
    const int e = blockIdx.x * 256 + threadIdx.x;
    if (e >= E_EDGES) return;
    const int s = src[e];
    const int d = dst[e];
    const float4* ps = (const float4*)(s_src + (size_t)s * HEADS);
    const float4* pd = (const float4*)(s_dst + (size_t)d * HEADS);
    const float4 s0 = ps[0], s1 = ps[1], d0 = pd[0], d1 = pd[1];
    float sc[8] = {s0.x + d0.x, s0.y + d0.y, s0.z + d0.z, s0.w + d0.w,
                   s1.x + d1.x, s1.y + d1.y, s1.z + d1.z, s1.w + d1.w};
#pragma unroll
    for (int h = 0; h < 8; h++) {
        float v = sc[h];
        v = v > 0.f ? v : SLOPE * v;
        atomicAdd(denom + (size_t)s * HEADS + h, __expf(v));
    }
}

// ---------------------------------------------------------------------------
// K2b: denom -> 1/denom (in place); unused (empty-segment) entries become inf
// ---------------------------------------------------------------------------
__global__ __launch_bounds__(256) void recip_kernel(float* __restrict__ denom)
{
    const int i = blockIdx.x * 256 + threadIdx.x;
    if (i < N_NODES * HEADS) denom[i] = __frcp_rn(denom[i]);
}

// ---------------------------------------------------------------------------
// K3: attention[e][h] = exp(leakyrelu(score)) * rdenom[src][h]
// ---------------------------------------------------------------------------
__global__ __launch_bounds__(256) void norm_kernel(
    const int* __restrict__ src, const int* __restrict__ dst,
    const float* __restrict__ s_src, const float* __restrict__ s_dst,
    const float* __restrict__ rdenom, float* __restrict__ att)
{
    const int e = blockIdx.x * 256 + threadIdx.x;
    if (e >= E_EDGES) return;
    const int s = src[e];
    const int d = dst[e];
    const float4* ps = (const float4*)(s_src + (size_t)s * HEADS);
    const float4* pd = (const float4*)(s_dst + (size_t)d * HEADS);
    const float4 s0 = ps[0], s1 = ps[1], d0 = pd[0], d1 = pd[1];
    const float4* pr = (const float4*)(rdenom + (size_t)s * HEADS);
    const float4 r0 = pr[0], r1 = pr[1];
    float sc[8] = {s0.x + d0.x, s0.y + d0.y, s0.z + d0.z, s0.w + d0.w,
                   s1.x + d1.x, s1.y + d1.y, s1.z + d1.z, s1.w + d1.w};
    float rd[8] = {r0.x, r0.y, r0.z, r0.w, r1.x, r1.y, r1.z, r1.w};
    float o[8];
#pragma unroll
    for (int h = 0; h < 8; h++) {
        float v = sc[h];
        v = v > 0.f ? v : SLOPE * v;
        o[h] = __expf(v) * rd[h];
    }
    float4* po = (float4*)(att + (size_t)e * HEADS);
    po[0] = make_float4(o[0], o[1], o[2], o[3]);
    po[1] = make_float4(o[4], o[5], o[6], o[7]);
}

extern "C" void kernel_launch(void* const* d_in, const int* in_sizes, int n_in,
                              void* d_out, int out_size, void* d_ws, size_t ws_size,
                              hipStream_t stream)
{
    const float* x    = (const float*)d_in[0];
    const int*   edge = (const int*)d_in[1];
    const float* W    = (const float*)d_in[2];
    const float* a    = (const float*)d_in[3];

    float* out = (float*)d_out;
    float* att = out;                                 // (E, HEADS)
    float* wx  = out + (size_t)E_EDGES * HEADS;       // (N, ATT)

    float* ws    = (float*)d_ws;
    float* s_src = ws;                                // N*HEADS
    float* s_dst = s_src + (size_t)N_NODES * HEADS;   // N*HEADS
    float* denom = s_dst + (size_t)N_NODES * HEADS;   // N*HEADS

    const int* src = edge;                 // edge[0][0][:]
    const int* dst = edge + E_EDGES;       // edge[0][1][:]

    hipMemsetAsync(denom, 0, (size_t)N_NODES * HEADS * sizeof(float), stream);

    const int gemm_blocks = (N_NODES + 127) / 128;    // 782
    gemm_s_kernel<<<gemm_blocks, 256, 0, stream>>>(x, W, a, wx, s_src, s_dst);

    const int eblocks = (E_EDGES + 255) / 256;        // 12500
    denom_kernel<<<eblocks, 256, 0, stream>>>(src, dst, s_src, s_dst, denom);

    const int nblocks = (N_NODES * HEADS + 255) / 256;
    recip_kernel<<<nblocks, 256, 0, stream>>>(denom);

    norm_kernel<<<eblocks, 256, 0, stream>>>(src, dst, s_src, s_dst, denom, att);
}